// Round 5
// baseline (680.781 us; speedup 1.0000x reference)
//
#include <hip/hip_runtime.h>
#include <math.h>

// N=8192 all-pairs wind-influence graph. Output: [edge_attr f32 N*N][mask01 f32 N*N]
//
// Round 7: full-row block ownership. Previously each output row (32 KiB) was
// split across two blocks (TJ=4096) -> row write streams stitched from two CUs,
// per-block streams had 16-KiB gaps. Now TJ=8192: each thread owns 8 j's, each
// block owns TI=16 COMPLETE rows -> one contiguous 512-KiB ev stream per block,
// then one contiguous mask stream (phase 2), matching the access shape of the
// 6.25 TB/s harness fills. Numerics BIT-IDENTICAL to round 6.
// Mask bits: 16 rows x 8 bits packed in two u64s during phase 1.
// Diagonal (a==0) falls into the slow path; j!=i kills it as before.

#define NN 8192
#define TI 16      // i-rows per block (full rows)
#define TJ 8192    // j-cols per block = 1024 threads * 8

#define ACUT 1.9e-4f   // a > ACUT  =>  dist > 175.6 km  =>  influence < 0.26 < 0.3

typedef float floatx4 __attribute__((ext_vector_type(4)));

__global__ __launch_bounds__(1024) void dyn_graph_kernel(
    const float* __restrict__ pos,     // (N,2): lat, lon (degrees)
    const float* __restrict__ wspd,
    const float* __restrict__ wdir,
    float* __restrict__ out)           // 2*N*N floats
{
    __shared__ __align__(16) float irow[TI * 12];

    const int tid   = threadIdx.x;
    const int i0    = blockIdx.y * TI;
    const int jbase = tid * 8;         // grid.x == 1: block spans the full row

    const float DEG2RAD = 0.017453292519943295f;

    // ---- stage i-side per-point values into LDS (once per block) ----
    if (tid < TI) {
        int i = i0 + tid;
        float latr = pos[2 * i]     * DEG2RAD;
        float lonr = pos[2 * i + 1] * DEG2RAD;
        float wr   = wdir[i]        * DEG2RAD;
        float s, c, hs, hc, hsl, hcl, sl, cl, swr, cwr;
        sincosf(latr,        &s,   &c);
        sincosf(0.5f * latr, &hs,  &hc);
        sincosf(0.5f * lonr, &hsl, &hcl);
        sincosf(lonr,        &sl,  &cl);
        sincosf(wr,          &swr, &cwr);
        float* p = &irow[tid * 12];
        p[0] = s;   p[1] = c;   p[2]  = hs;  p[3]  = hc;
        p[4] = hsl; p[5] = hcl; p[6]  = sl;  p[7]  = cl;
        p[8] = swr; p[9] = cwr; p[10] = wspd[i] / 10.0f;
        p[11] = 0.0f;
    }

    // ---- j-side per-point values (8 j's per thread), reused across 16 rows ----
    float4 q0 = *(const float4*)(pos + 2 * jbase);
    float4 q1 = *(const float4*)(pos + 2 * jbase + 4);
    float4 q2 = *(const float4*)(pos + 2 * jbase + 8);
    float4 q3 = *(const float4*)(pos + 2 * jbase + 12);
    float jlat[8] = { q0.x, q0.z, q1.x, q1.z, q2.x, q2.z, q3.x, q3.z };
    float jlon[8] = { q0.y, q0.w, q1.y, q1.w, q2.y, q2.w, q3.y, q3.w };

    float js[8], jc[8], jhs[8], jhc[8], jhsl[8], jhcl[8], jsl[8], jcl[8];
    #pragma unroll
    for (int k = 0; k < 8; ++k) {
        float latr = jlat[k] * DEG2RAD;
        float lonr = jlon[k] * DEG2RAD;
        sincosf(latr,        &js[k],   &jc[k]);
        sincosf(0.5f * latr, &jhs[k],  &jhc[k]);
        sincosf(0.5f * lonr, &jhsl[k], &jhcl[k]);
        sincosf(lonr,        &jsl[k],  &jcl[k]);
    }

    __syncthreads();

    // mask bits: row r, lane-k -> bit (8*r + k); rows 0-7 in mlo, 8-15 in mhi
    unsigned long long mlo = 0ULL, mhi = 0ULL;

    // ---- phase 1: compute + ev stores (single contiguous write stream) ----
    #pragma unroll 2
    for (int r = 0; r < TI; ++r) {
        const float4* p4 = (const float4*)&irow[r * 12];
        float4 A = p4[0], B = p4[1], C = p4[2];
        const float is  = A.x, ic  = A.y, ihs = A.z, ihc = A.w;
        const float ihsl= B.x, ihcl= B.y, isl = B.z, icl = B.w;
        const float swr = C.x, cwr = C.y, ws10= C.z;
        const int i = i0 + r;

        float ev[8];
        unsigned int byte = 0u;
        #pragma unroll
        for (int k = 0; k < 8; ++k) {
            // cheap haversine 'a' via cancellation-safe half-angle products
            float shlat = jhs[k] * ihc - jhc[k] * ihs;     // sin((lat2-lat1)/2)
            float shlon = jhsl[k] * ihcl - jhcl[k] * ihsl; // sin((lon2-lon1)/2)
            float cc = ic * jc[k];
            float a = shlat * shlat + cc * (shlon * shlon);

            ev[k] = 0.0f;

            if (a <= ACUT) {   // ~0.7% of pairs (plus diagonal) — slow path
                float ac = fmaxf(a, 1e-12f);               // upper clamp dead (a<=1.9e-4)
                // dist = 2R*asin(sqrt(ac)); series exact to <3e-9 rel in range
                float sq = sqrtf(ac);
                float dist = 12742.0f * sq * __builtin_fmaf(ac, 0.16666667f, 1.0f);

                float sdlon = jsl[k] * icl - jcl[k] * isl;     // sin(dlon)
                float cdlon = jcl[k] * icl + jsl[k] * isl;     // cos(dlon)
                float x = sdlon * jc[k];
                float y = ic * js[k] - (is * jc[k]) * cdlon;

                float num = y * cwr + x * swr;                 // cos(atan2(x,y)-wr)*|v|
                float h2  = x * x + y * y;
                float align = num * rsqrtf(h2);

                float infl = align * ws10 * __expf(dist * -0.01f);
                // dist <= 175.7 < 300 always here: MAX_DIST test dropped
                bool m = (jbase + k != i) && (infl > 0.3f);
                ev[k] = m ? infl : 0.0f;
                byte |= (m ? 1u : 0u) << k;
            }
        }

        // accumulate mask byte (defined shifts: amount always < 64)
        unsigned long long val = (unsigned long long)byte << ((8 * r) & 63);
        mlo |= (r < 8) ? val : 0ULL;
        mhi |= (r < 8) ? 0ULL : val;

        size_t idx = (size_t)i * NN + jbase;
        floatx4 e0 = { ev[0], ev[1], ev[2], ev[3] };
        floatx4 e1 = { ev[4], ev[5], ev[6], ev[7] };
        __builtin_nontemporal_store(e0, (floatx4*)(out + idx));
        __builtin_nontemporal_store(e1, (floatx4*)(out + idx + 4));
    }

    // ---- phase 2: mask stores only (single contiguous write stream) ----
    float* outm = out + (size_t)NN * NN;
    #pragma unroll
    for (int r = 0; r < TI; ++r) {
        unsigned int byte = (unsigned int)(((r < 8 ? mlo : mhi) >> (8 * (r & 7))) & 0xFFULL);
        floatx4 m0 = { (float)(byte & 1u),        (float)((byte >> 1) & 1u),
                       (float)((byte >> 2) & 1u), (float)((byte >> 3) & 1u) };
        floatx4 m1 = { (float)((byte >> 4) & 1u), (float)((byte >> 5) & 1u),
                       (float)((byte >> 6) & 1u), (float)((byte >> 7) & 1u) };
        size_t idx = (size_t)(i0 + r) * NN + jbase;
        __builtin_nontemporal_store(m0, (floatx4*)(outm + idx));
        __builtin_nontemporal_store(m1, (floatx4*)(outm + idx + 4));
    }
}

extern "C" void kernel_launch(void* const* d_in, const int* in_sizes, int n_in,
                              void* d_out, int out_size, void* d_ws, size_t ws_size,
                              hipStream_t stream) {
    const float* pos  = (const float*)d_in[0];
    const float* wspd = (const float*)d_in[1];
    const float* wdir = (const float*)d_in[2];
    float* out = (float*)d_out;

    dim3 grid(1, NN / TI);   // (1, 512) — each block owns 16 full rows
    dim3 block(1024);
    dyn_graph_kernel<<<grid, block, 0, stream>>>(pos, wspd, wdir, out);
}

// Round 6
// 528.027 us; speedup vs baseline: 1.2893x; 1.2893x over previous
//
#include <hip/hip_runtime.h>
#include <math.h>

// N=8192 all-pairs wind-influence graph. Output: [edge_attr f32 N*N][mask01 f32 N*N]
//
// Round 8: revert round-7 (VGPR spill at 8 j's/thread: launch_bounds(1024)
// caps at 128 VGPR -> scratch traffic on a store-bound kernel, +150 us).
// Back to the round-6 structure (best: 529 us) with one low-risk tweak:
//   TI 32->64 at unchanged TJ=4096 / 4 j's per thread.
//   - VGPR stays ~round-6 level (+2 u64 mask regs only, no spill).
//   - 256 blocks = 1/CU, single dispatch batch (no second block-wave).
//   - sincosf prologue amortized over 2x rows.
// Phase 1: compute + ev stores (one write stream), mask bits packed into four
// u64s via branch-free selects (no dynamic reg indexing). Phase 2: store-only
// mask expansion, fully unrolled (static shifts). Numerics BIT-IDENTICAL.
// Diagonal (a==0) falls into the slow path; j!=i kills it as before.

#define NN 8192
#define TI 64      // i-rows per block
#define TJ 4096    // j-cols per block = 1024 threads * 4

#define ACUT 1.9e-4f   // a > ACUT  =>  dist > 175.6 km  =>  influence < 0.26 < 0.3

typedef float floatx4 __attribute__((ext_vector_type(4)));

__global__ __launch_bounds__(1024) void dyn_graph_kernel(
    const float* __restrict__ pos,     // (N,2): lat, lon (degrees)
    const float* __restrict__ wspd,
    const float* __restrict__ wdir,
    float* __restrict__ out)           // 2*N*N floats
{
    __shared__ __align__(16) float irow[TI * 12];

    const int tid   = threadIdx.x;
    const int i0    = blockIdx.y * TI;
    const int jbase = blockIdx.x * TJ + tid * 4;

    const float DEG2RAD = 0.017453292519943295f;

    // ---- stage i-side per-point values into LDS (once per block) ----
    if (tid < TI) {
        int i = i0 + tid;
        float latr = pos[2 * i]     * DEG2RAD;
        float lonr = pos[2 * i + 1] * DEG2RAD;
        float wr   = wdir[i]        * DEG2RAD;
        float s, c, hs, hc, hsl, hcl, sl, cl, swr, cwr;
        sincosf(latr,        &s,   &c);
        sincosf(0.5f * latr, &hs,  &hc);
        sincosf(0.5f * lonr, &hsl, &hcl);
        sincosf(lonr,        &sl,  &cl);
        sincosf(wr,          &swr, &cwr);
        float* p = &irow[tid * 12];
        p[0] = s;   p[1] = c;   p[2]  = hs;  p[3]  = hc;
        p[4] = hsl; p[5] = hcl; p[6]  = sl;  p[7]  = cl;
        p[8] = swr; p[9] = cwr; p[10] = wspd[i] / 10.0f;
        p[11] = 0.0f;
    }

    // ---- j-side per-point values (4 j's per thread), reused across 64 rows ----
    float4 p01 = *(const float4*)(pos + 2 * jbase);      // pos[2j .. 2j+3]
    float4 p23 = *(const float4*)(pos + 2 * jbase + 4);  // pos[2j+4 .. 2j+7]
    float jlat[4] = { p01.x, p01.z, p23.x, p23.z };
    float jlon[4] = { p01.y, p01.w, p23.y, p23.w };

    float js[4], jc[4], jhs[4], jhc[4], jhsl[4], jhcl[4], jsl[4], jcl[4];
    #pragma unroll
    for (int k = 0; k < 4; ++k) {
        float latr = jlat[k] * DEG2RAD;
        float lonr = jlon[k] * DEG2RAD;
        sincosf(latr,        &js[k],   &jc[k]);
        sincosf(0.5f * latr, &jhs[k],  &jhc[k]);
        sincosf(0.5f * lonr, &jhsl[k], &jhcl[k]);
        sincosf(lonr,        &jsl[k],  &jcl[k]);
    }

    __syncthreads();

    // mask bits: row r, lane-k -> bit (4*r + k) within m[r/16]; 16 rows per u64
    unsigned long long m0 = 0ULL, m1 = 0ULL, m2 = 0ULL, m3 = 0ULL;

    // ---- phase 1: compute + ev stores (single write stream) ----
    #pragma unroll 2
    for (int r = 0; r < TI; ++r) {
        const float4* p4 = (const float4*)&irow[r * 12];
        float4 A = p4[0], B = p4[1], C = p4[2];
        const float is  = A.x, ic  = A.y, ihs = A.z, ihc = A.w;
        const float ihsl= B.x, ihcl= B.y, isl = B.z, icl = B.w;
        const float swr = C.x, cwr = C.y, ws10= C.z;
        const int i = i0 + r;

        float ev[4];
        unsigned int nib = 0u;
        #pragma unroll
        for (int k = 0; k < 4; ++k) {
            // cheap haversine 'a' via cancellation-safe half-angle products
            float shlat = jhs[k] * ihc - jhc[k] * ihs;     // sin((lat2-lat1)/2)
            float shlon = jhsl[k] * ihcl - jhcl[k] * ihsl; // sin((lon2-lon1)/2)
            float cc = ic * jc[k];
            float a = shlat * shlat + cc * (shlon * shlon);

            ev[k] = 0.0f;

            if (a <= ACUT) {   // ~0.7% of pairs (plus diagonal) — slow path
                float ac = fmaxf(a, 1e-12f);               // upper clamp dead (a<=1.9e-4)
                // dist = 2R*asin(sqrt(ac)); series exact to <3e-9 rel in range
                float sq = sqrtf(ac);
                float dist = 12742.0f * sq * __builtin_fmaf(ac, 0.16666667f, 1.0f);

                float sdlon = jsl[k] * icl - jcl[k] * isl;     // sin(dlon)
                float cdlon = jcl[k] * icl + jsl[k] * isl;     // cos(dlon)
                float x = sdlon * jc[k];
                float y = ic * js[k] - (is * jc[k]) * cdlon;

                float num = y * cwr + x * swr;                 // cos(atan2(x,y)-wr)*|v|
                float h2  = x * x + y * y;
                float align = num * rsqrtf(h2);

                float infl = align * ws10 * __expf(dist * -0.01f);
                // dist <= 175.7 < 300 always here: MAX_DIST test dropped
                bool m = (jbase + k != i) && (infl > 0.3f);
                ev[k] = m ? infl : 0.0f;
                nib |= (m ? 1u : 0u) << k;
            }
        }

        // accumulate mask nibble into m0..m3 (branch-free, shift amount < 64)
        unsigned long long val = (unsigned long long)nib << ((4 * r) & 63);
        m0 |= (r < 16)            ? val : 0ULL;
        m1 |= (r >= 16 && r < 32) ? val : 0ULL;
        m2 |= (r >= 32 && r < 48) ? val : 0ULL;
        m3 |= (r >= 48)           ? val : 0ULL;

        size_t idx = (size_t)i * NN + jbase;
        floatx4 evv = { ev[0], ev[1], ev[2], ev[3] };
        __builtin_nontemporal_store(evv, (floatx4*)(out + idx));
    }

    // ---- phase 2: mask stores only (single write stream, fully unrolled) ----
    float* outm = out + (size_t)NN * NN;
    #pragma unroll
    for (int r = 0; r < TI; ++r) {
        unsigned long long src = (r < 16) ? m0 : (r < 32) ? m1 : (r < 48) ? m2 : m3;
        unsigned int nib = (unsigned int)((src >> (4 * (r & 15))) & 0xFULL);
        floatx4 mvv = { (float)(nib & 1u), (float)((nib >> 1) & 1u),
                        (float)((nib >> 2) & 1u), (float)((nib >> 3) & 1u) };
        size_t idx = (size_t)(i0 + r) * NN + jbase;
        __builtin_nontemporal_store(mvv, (floatx4*)(outm + idx));
    }
}

extern "C" void kernel_launch(void* const* d_in, const int* in_sizes, int n_in,
                              void* d_out, int out_size, void* d_ws, size_t ws_size,
                              hipStream_t stream) {
    const float* pos  = (const float*)d_in[0];
    const float* wspd = (const float*)d_in[1];
    const float* wdir = (const float*)d_in[2];
    float* out = (float*)d_out;

    dim3 grid(NN / TJ, NN / TI);   // (2, 128) = 256 blocks, 1 per CU
    dim3 block(1024);
    dyn_graph_kernel<<<grid, block, 0, stream>>>(pos, wspd, wdir, out);
}